// Round 7
// baseline (126.681 us; speedup 1.0000x reference)
//
#include <hip/hip_runtime.h>

// x:  [N=4, C=256, H=56, W=56] fp32
// w1: [N, 1, 32, 9,  H, W]     (3x3, pad 1)
// w2: [N, 1, 32, 25, H, W]     (5x5, pad 2)
// out:[N, 2, 1, C, H, W]
// out[n,b,c,h,w] = sum_p wB[n, c%32, p, h, w] * x[n, c, h+dh, w+dw] (zero pad)
//
// R7 = R6 + (1) software-pipelined weight stream: w2 rows rotate cur/nxt so
// di+1's 5 float4 loads are in flight while di computes (compiler emits
// partial vmcnt waits instead of per-iter vmcnt(0)); di=0 w2 rows and ALL
// 9 w1 rows are issued before __syncthreads so their HBM latency hides
// behind x staging; 3x3 loop then runs with zero global loads.
// (2) gsel block-pair at stride 8 -> same XCD under round-robin, so the
// second fetch of the same weight planes hits that XCD's L2 (R6 put the
// pair 4 apart -> different XCDs -> duplicated L2/L3 traffic).

#define N_  4
#define C_  256
#define H_  56
#define W_  56
#define HW_ 3136
#define WC_ 32

#define TILE    14
#define LROWS   18   // TILE + 4 halo rows
#define LSTRIDE 64   // x col c -> slot c+2; slots 0,1 & 58,59 zero halo

__global__ __launch_bounds__(256) void lconv_kernel(
    const float* __restrict__ x,
    const float* __restrict__ w1,
    const float* __restrict__ w2,
    float* __restrict__ out)
{
    __shared__ float lds[4 * LROWS * LSTRIDE];   // 18432 B

    const int b     = blockIdx.x;        // 0..1023
    const int tile  = b & 3;
    const int vlow  = (b >> 2) & 1;
    const int gsel  = (b >> 3) & 1;      // stride 8 -> gsel-pair on same XCD
    const int vhigh = (b >> 4) & 15;
    const int n     = b >> 8;
    const int v     = (vhigh << 1) | vlow;
    const int r0    = tile * TILE;
    const int nv    = n * WC_ + v;
    const int tid   = threadIdx.x;

    const int row = tid / 14;            // 0..18 (compute uses 0..13)
    const int s   = tid - row * 14;
    const int wb  = 4 * s;               // 0,4,...,52
    const int h   = r0 + row;
    const int hc  = (h < H_) ? h : (H_ - 1);   // clamp so dead-thread preloads stay in-bounds
    const int hw  = hc * W_ + wb;

    const float* w1t = w1 + (size_t)nv * 9  * HW_ + hw;
    const float* w2t = w2 + (size_t)nv * 25 * HW_ + hw;

    // ---- weight preloads issued BEFORE staging: latency overlaps staging ----
    float4 w2cur[5], w2nxt[5];
    #pragma unroll
    for (int dj = 0; dj < 5; ++dj)
        w2cur[dj] = *(const float4*)(w2t + (size_t)dj * HW_);
    float4 w1all[9];
    #pragma unroll
    for (int p = 0; p < 9; ++p)
        w1all[p] = *(const float4*)(w1t + (size_t)p * HW_);

    // ---- stage x: 4 planes x 18 rows x 56 cols; zero OOB rows ----
    for (int idx = tid; idx < 4 * LROWS * 14; idx += 256) {
        const int c4 = idx % 14;
        const int t2 = idx / 14;
        const int lr = t2 % LROWS;
        const int pl = t2 / LROWS;
        const int gr = r0 - 2 + lr;
        float4 val = make_float4(0.f, 0.f, 0.f, 0.f);
        if (gr >= 0 && gr < H_) {
            const int ch = gsel * 128 + pl * 32 + v;
            val = *(const float4*)(x + (size_t)(n * C_ + ch) * HW_ + gr * W_ + c4 * 4);
        }
        float* lp = &lds[(pl * LROWS + lr) * LSTRIDE + 4 * c4 + 2];
        *(float2*)(lp)     = make_float2(val.x, val.y);
        *(float2*)(lp + 2) = make_float2(val.z, val.w);
    }
    // zero column halos: slots 0,1 (x cols -2,-1) and 58,59 (x cols 56,57)
    for (int idx = tid; idx < 4 * LROWS * 4; idx += 256) {
        const int k  = idx & 3;
        const int t2 = idx >> 2;
        const int lr = t2 % LROWS;
        const int pl = t2 / LROWS;
        const int slot = (k < 2) ? k : (56 + k);
        lds[(pl * LROWS + lr) * LSTRIDE + slot] = 0.f;
    }
    __syncthreads();

    if (tid >= TILE * 14) return;        // 196 compute threads; no barriers below

    const int c0 = gsel * 128 + v;

    // ================= 5x5 branch: pipelined w2 stream =================
    float a2[4][4];
    #pragma unroll
    for (int g = 0; g < 4; ++g)
        #pragma unroll
        for (int p = 0; p < 4; ++p) a2[g][p] = 0.f;

    #pragma unroll 1
    for (int di = 0; di < 5; ++di) {
        if (di < 4) {
            #pragma unroll
            for (int dj = 0; dj < 5; ++dj)
                w2nxt[dj] = *(const float4*)(w2t + (size_t)((di + 1) * 5 + dj) * HW_);
        }
        #pragma unroll
        for (int g = 0; g < 4; ++g) {
            const float* lp = &lds[(g * LROWS + row + di) * LSTRIDE + wb];
            const float4 xa  = *(const float4*)(lp);
            const float4 xb4 = *(const float4*)(lp + 4);
            const float xw[8] = {xa.x, xa.y, xa.z, xa.w, xb4.x, xb4.y, xb4.z, xb4.w};
            #pragma unroll
            for (int dj = 0; dj < 5; ++dj) {
                const float* wr = (const float*)&w2cur[dj];
                #pragma unroll
                for (int p = 0; p < 4; ++p)
                    a2[g][p] += wr[p] * xw[p + dj];
            }
        }
        if (di < 4) {
            #pragma unroll
            for (int dj = 0; dj < 5; ++dj) w2cur[dj] = w2nxt[dj];
        }
    }

    float* o2 = out + ((size_t)(n * 2 + 1) * C_ + c0) * HW_ + hw;
    #pragma unroll
    for (int g = 0; g < 4; ++g)
        *(float4*)(o2 + (size_t)g * WC_ * HW_) =
            make_float4(a2[g][0], a2[g][1], a2[g][2], a2[g][3]);

    // ================= 3x3 branch: weights already resident =================
    float a1[4][4];
    #pragma unroll
    for (int g = 0; g < 4; ++g)
        #pragma unroll
        for (int p = 0; p < 4; ++p) a1[g][p] = 0.f;

    #pragma unroll 1
    for (int di = 0; di < 3; ++di) {
        #pragma unroll
        for (int g = 0; g < 4; ++g) {
            // x rows h-1+di -> LDS row row+1+di; same 8-float window
            const float* lp = &lds[(g * LROWS + row + 1 + di) * LSTRIDE + wb];
            const float4 xa  = *(const float4*)(lp);
            const float4 xb4 = *(const float4*)(lp + 4);
            const float xw[8] = {xa.x, xa.y, xa.z, xa.w, xb4.x, xb4.y, xb4.z, xb4.w};
            #pragma unroll
            for (int dj = 0; dj < 3; ++dj) {
                const float* wr = (const float*)&w1all[di * 3 + dj];
                #pragma unroll
                for (int p = 0; p < 4; ++p)
                    a1[g][p] += wr[p] * xw[p + dj + 1];
            }
        }
    }

    float* o1 = out + ((size_t)(n * 2 + 0) * C_ + c0) * HW_ + hw;
    #pragma unroll
    for (int g = 0; g < 4; ++g)
        *(float4*)(o1 + (size_t)g * WC_ * HW_) =
            make_float4(a1[g][0], a1[g][1], a1[g][2], a1[g][3]);
}

extern "C" void kernel_launch(void* const* d_in, const int* in_sizes, int n_in,
                              void* d_out, int out_size, void* d_ws, size_t ws_size,
                              hipStream_t stream) {
    const float* x  = (const float*)d_in[0];
    const float* w1 = (const float*)d_in[1];
    const float* w2 = (const float*)d_in[2];
    float* out = (float*)d_out;

    dim3 grid(1024), block(256);   // 4 blocks/CU
    hipLaunchKernelGGL(lconv_kernel, grid, block, 0, stream, x, w1, w2, out);
}

// Round 8
// 112.269 us; speedup vs baseline: 1.1284x; 1.1284x over previous
//
#include <hip/hip_runtime.h>

// x:  [N=4, C=256, H=56, W=56] fp32
// w1: [N, 1, 32, 9,  H, W]     (3x3, pad 1)
// w2: [N, 1, 32, 25, H, W]     (5x5, pad 2)
// out:[N, 2, 1, C, H, W]
// out[n,b,c,h,w] = sum_p wB[n, c%32, p, h, w] * x[n, c, h+dh, w+dw] (zero pad)
//
// R8 = R6 structure + two fixes proven by R7's counters:
//  (1) LSTRIDE 64 -> 68: 64 dwords = 0 mod 32 banks made every g-plane and
//      di-row alias onto the same banks (SQ_LDS_BANK_CONFLICT = 5.3M cyc).
//      68 mod 32 = 4 staggers rows by 4 banks; row base stays 16B-aligned
//      so ds_read_b128 still works.
//  (2) NO pre-barrier weight preloads (R7 spilled them: WRITE 62MB vs 25.7MB
//      output). Weight stream is pipelined cur/nxt INSIDE each branch loop,
//      after the barrier, so live range never crosses the staging code.

#define N_  4
#define C_  256
#define H_  56
#define W_  56
#define HW_ 3136
#define WC_ 32

#define TILE    14
#define LROWS   18   // TILE + 4 halo rows
#define LSTRIDE 68   // x col c -> slot c+2; slots 0,1 & 58,59 zero halo

__global__ __launch_bounds__(256) void lconv_kernel(
    const float* __restrict__ x,
    const float* __restrict__ w1,
    const float* __restrict__ w2,
    float* __restrict__ out)
{
    __shared__ float lds[4 * LROWS * LSTRIDE];   // 19584 B

    const int b     = blockIdx.x;        // 0..1023
    const int tile  = b & 3;
    const int vlow  = (b >> 2) & 1;
    const int gsel  = (b >> 3) & 1;      // stride 8 -> gsel-pair on same XCD
    const int vhigh = (b >> 4) & 15;
    const int n     = b >> 8;
    const int v     = (vhigh << 1) | vlow;
    const int r0    = tile * TILE;
    const int nv    = n * WC_ + v;
    const int tid   = threadIdx.x;

    // ---- stage x: 4 planes x 18 rows x 56 cols; zero OOB rows ----
    for (int idx = tid; idx < 4 * LROWS * 14; idx += 256) {
        const int c4 = idx % 14;
        const int t2 = idx / 14;
        const int lr = t2 % LROWS;
        const int pl = t2 / LROWS;
        const int gr = r0 - 2 + lr;
        float4 val = make_float4(0.f, 0.f, 0.f, 0.f);
        if (gr >= 0 && gr < H_) {
            const int ch = gsel * 128 + pl * 32 + v;
            val = *(const float4*)(x + (size_t)(n * C_ + ch) * HW_ + gr * W_ + c4 * 4);
        }
        float* lp = &lds[(pl * LROWS + lr) * LSTRIDE + 4 * c4 + 2];
        *(float2*)(lp)     = make_float2(val.x, val.y);
        *(float2*)(lp + 2) = make_float2(val.z, val.w);
    }
    // zero column halos: slots 0,1 (x cols -2,-1) and 58,59 (x cols 56,57)
    for (int idx = tid; idx < 4 * LROWS * 4; idx += 256) {
        const int k  = idx & 3;
        const int t2 = idx >> 2;
        const int lr = t2 % LROWS;
        const int pl = t2 / LROWS;
        const int slot = (k < 2) ? k : (56 + k);
        lds[(pl * LROWS + lr) * LSTRIDE + slot] = 0.f;
    }
    __syncthreads();

    if (tid >= TILE * 14) return;        // 196 compute threads; no barriers below

    const int row = tid / 14;            // 0..13
    const int s   = tid - row * 14;
    const int wb  = 4 * s;               // 0,4,...,52
    const int h   = r0 + row;
    const int hw  = h * W_ + wb;

    const float* w1t = w1 + (size_t)nv * 9  * HW_ + hw;
    const float* w2t = w2 + (size_t)nv * 25 * HW_ + hw;
    const int c0 = gsel * 128 + v;

    // ================= 5x5 branch: pipelined w2 stream =================
    float a2[4][4];
    #pragma unroll
    for (int g = 0; g < 4; ++g)
        #pragma unroll
        for (int p = 0; p < 4; ++p) a2[g][p] = 0.f;

    float4 w2cur[5], w2nxt[5];
    #pragma unroll
    for (int dj = 0; dj < 5; ++dj)
        w2cur[dj] = *(const float4*)(w2t + (size_t)dj * HW_);

    #pragma unroll 1
    for (int di = 0; di < 5; ++di) {
        if (di < 4) {
            #pragma unroll
            for (int dj = 0; dj < 5; ++dj)
                w2nxt[dj] = *(const float4*)(w2t + (size_t)((di + 1) * 5 + dj) * HW_);
        }
        #pragma unroll
        for (int g = 0; g < 4; ++g) {
            const float* lp = &lds[(g * LROWS + row + di) * LSTRIDE + wb];
            const float4 xa  = *(const float4*)(lp);
            const float4 xb4 = *(const float4*)(lp + 4);
            const float xw[8] = {xa.x, xa.y, xa.z, xa.w, xb4.x, xb4.y, xb4.z, xb4.w};
            #pragma unroll
            for (int dj = 0; dj < 5; ++dj) {
                const float* wr = (const float*)&w2cur[dj];
                #pragma unroll
                for (int p = 0; p < 4; ++p)
                    a2[g][p] += wr[p] * xw[p + dj];
            }
        }
        if (di < 4) {
            #pragma unroll
            for (int dj = 0; dj < 5; ++dj) w2cur[dj] = w2nxt[dj];
        }
    }

    float* o2 = out + ((size_t)(n * 2 + 1) * C_ + c0) * HW_ + hw;
    #pragma unroll
    for (int g = 0; g < 4; ++g)
        *(float4*)(o2 + (size_t)g * WC_ * HW_) =
            make_float4(a2[g][0], a2[g][1], a2[g][2], a2[g][3]);

    // ================= 3x3 branch: pipelined w1 stream =================
    float a1[4][4];
    #pragma unroll
    for (int g = 0; g < 4; ++g)
        #pragma unroll
        for (int p = 0; p < 4; ++p) a1[g][p] = 0.f;

    float4 w1cur[3], w1nxt[3];
    #pragma unroll
    for (int dj = 0; dj < 3; ++dj)
        w1cur[dj] = *(const float4*)(w1t + (size_t)dj * HW_);

    #pragma unroll 1
    for (int di = 0; di < 3; ++di) {
        if (di < 2) {
            #pragma unroll
            for (int dj = 0; dj < 3; ++dj)
                w1nxt[dj] = *(const float4*)(w1t + (size_t)((di + 1) * 3 + dj) * HW_);
        }
        #pragma unroll
        for (int g = 0; g < 4; ++g) {
            // x rows h-1+di -> LDS row row+1+di
            const float* lp = &lds[(g * LROWS + row + 1 + di) * LSTRIDE + wb];
            const float4 xa  = *(const float4*)(lp);
            const float4 xb4 = *(const float4*)(lp + 4);
            const float xw[8] = {xa.x, xa.y, xa.z, xa.w, xb4.x, xb4.y, xb4.z, xb4.w};
            #pragma unroll
            for (int dj = 0; dj < 3; ++dj) {
                const float* wr = (const float*)&w1cur[dj];
                #pragma unroll
                for (int p = 0; p < 4; ++p)
                    a1[g][p] += wr[p] * xw[p + dj + 1];
            }
        }
        if (di < 2) {
            #pragma unroll
            for (int dj = 0; dj < 3; ++dj) w1cur[dj] = w1nxt[dj];
        }
    }

    float* o1 = out + ((size_t)(n * 2 + 0) * C_ + c0) * HW_ + hw;
    #pragma unroll
    for (int g = 0; g < 4; ++g)
        *(float4*)(o1 + (size_t)g * WC_ * HW_) =
            make_float4(a1[g][0], a1[g][1], a1[g][2], a1[g][3]);
}

extern "C" void kernel_launch(void* const* d_in, const int* in_sizes, int n_in,
                              void* d_out, int out_size, void* d_ws, size_t ws_size,
                              hipStream_t stream) {
    const float* x  = (const float*)d_in[0];
    const float* w1 = (const float*)d_in[1];
    const float* w2 = (const float*)d_in[2];
    float* out = (float*)d_out;

    dim3 grid(1024), block(256);   // 4 blocks/CU
    hipLaunchKernelGGL(lconv_kernel, grid, block, 0, stream, x, w1, w2, out);
}